// Round 2
// baseline (986.133 us; speedup 1.0000x reference)
//
#include <hip/hip_runtime.h>
#include <math.h>

#define N_ATOMS 51
#define VMIN_F  (-10.0f)
#define VMAX_F  (10.0f)
#define GAMMA_F (0.99f)
#define ACT     4
#define BLOCK   256
#define WPB     (BLOCK / 64)   // waves per block

__device__ __forceinline__ float wred_max(float v) {
#pragma unroll
    for (int off = 32; off; off >>= 1) v = fmaxf(v, __shfl_xor(v, off, 64));
    return v;
}
__device__ __forceinline__ float wred_sum(float v) {
#pragma unroll
    for (int off = 32; off; off >>= 1) v += __shfl_xor(v, off, 64);
    return v;
}

__global__ __launch_bounds__(BLOCK) void c51_kernel(
    const float* __restrict__ next_logits,   // [B,51]
    const float* __restrict__ old_logits,    // [B,4,51]
    const float* __restrict__ reward,        // [B]
    const float* __restrict__ done,          // [B]
    const int*   __restrict__ actions,       // [B]
    float* __restrict__ out,                 // out[0]=loss, out+1 = proj [B,51]
    int B)
{
    __shared__ float bins[WPB][64];
    __shared__ float wacc[WPB];

    const int lane  = threadIdx.x & 63;
    const int wid   = threadIdx.x >> 6;
    const int gwave = (blockIdx.x * blockDim.x + threadIdx.x) >> 6;
    const int nwav  = (gridDim.x * blockDim.x) >> 6;

    const float delta_z = 0.4f;              // (VMAX-VMIN)/(N-1) in f32
    const bool  active  = lane < N_ATOMS;
    // support z_j = VMIN + delta_z * j  (match numpy op order, no FMA)
    const float zj = __fadd_rn(VMIN_F, __fmul_rn(delta_z, (float)lane));

    float acc = 0.0f;

    const int iters = (B + nwav - 1) / nwav;
    for (int it = 0; it < iters; ++it) {
        const int  r     = gwave + it * nwav;
        const bool valid = r < B;

        // ---- softmax(next_logits[r]) ----
        float x = (valid && active) ? next_logits[(size_t)r * N_ATOMS + lane]
                                    : -INFINITY;
        float m = wred_max(x);
        float e = (valid && active) ? expf(__fsub_rn(x, m)) : 0.0f;
        float s = wred_sum(e);
        float p = valid ? __fdiv_rn(e, s) : 0.0f;

        // ---- Bellman projection (exact f32 op replication, no contraction) ----
        float wl = 0.0f, wu = 0.0f;
        int   li = 0,    ui = 0;
        if (valid) {
            float rw = reward[r];
            float db = (done[r] > 0.95f) ? 1.0f : 0.0f;
            float s1 = __fmul_rn(__fsub_rn(1.0f, db), GAMMA_F);
            float tz = __fadd_rn(rw, __fmul_rn(s1, zj));
            tz = fminf(fmaxf(tz, VMIN_F), VMAX_F);
            float b  = __fdiv_rn(__fsub_rn(tz, VMIN_F), delta_z);
            float lf = floorf(b);
            float uf = ceilf(b);
            li = (int)lf;
            ui = (int)uf;
            wl = __fmul_rn(p, __fsub_rn(uf, b));
            wu = __fmul_rn(p, __fsub_rn(b, lf));
        }

        // ---- scatter into per-wave LDS bins ----
        bins[wid][lane] = 0.0f;
        __syncthreads();
        if (valid && active) {
            atomicAdd(&bins[wid][li], wl);
            atomicAdd(&bins[wid][ui], wu);
        }
        __syncthreads();
        float proj = (valid && active) ? bins[wid][lane] : 0.0f;

        // ---- log_softmax(old_logits[r, actions[r], :]) ----
        float term = 0.0f;
        if (valid) {
            int a = actions[r];
            const float* op = old_logits + ((size_t)r * ACT + a) * N_ATOMS;
            float y  = active ? op[lane] : -INFINITY;
            float m2 = wred_max(y);
            float sh = __fsub_rn(y, m2);
            float e2 = active ? expf(sh) : 0.0f;
            float s2 = wred_sum(e2);
            float lp = __fsub_rn(sh, logf(s2));
            term = active ? __fmul_rn(proj, lp) : 0.0f;
        }
        acc += wred_sum(term);   // same value in all lanes

        // ---- write proj row ----
        if (valid && active) out[1 + (size_t)r * N_ATOMS + lane] = proj;
    }

    // ---- loss reduction: wave -> block -> global atomic ----
    if (lane == 0) wacc[wid] = acc;
    __syncthreads();
    if (threadIdx.x == 0) {
        float t = 0.0f;
#pragma unroll
        for (int i = 0; i < WPB; ++i) t += wacc[i];
        atomicAdd(out, -t / (float)B);
    }
}

extern "C" void kernel_launch(void* const* d_in, const int* in_sizes, int n_in,
                              void* d_out, int out_size, void* d_ws, size_t ws_size,
                              hipStream_t stream) {
    const float* next_logits = (const float*)d_in[0];
    const float* old_logits  = (const float*)d_in[1];
    const float* reward      = (const float*)d_in[2];
    const float* done        = (const float*)d_in[3];
    const int*   actions     = (const int*)d_in[4];
    float* out = (float*)d_out;
    const int B = in_sizes[2];   // reward element count

    // zero the loss accumulator slot (d_out is poisoned before every launch)
    hipMemsetAsync(d_out, 0, sizeof(float), stream);

    const int grid = 2048;       // 8192 waves -> 64 rows/wave at B=524288
    c51_kernel<<<grid, BLOCK, 0, stream>>>(next_logits, old_logits, reward,
                                           done, actions, out, B);
}

// Round 4
// 801.013 us; speedup vs baseline: 1.2311x; 1.2311x over previous
//
#include <hip/hip_runtime.h>
#include <math.h>

#define N_ATOMS 51
#define VMIN_F  (-10.0f)
#define VMAX_F  (10.0f)
#define GAMMA_F (0.99f)
#define ACT     4
#define BLOCK   256
#define WPB     (BLOCK / 64)   // waves per block
#define RPI     2              // rows per wave per iteration
#define GRID    2048

// ---- DPP-based wave64 reductions (VALU pipe, ~8cyc/step vs ~120cyc LDS shuffles) ----
#define DPP_F(OLDF, SRCF, CTRL, RMASK) \
  __int_as_float(__builtin_amdgcn_update_dpp(__float_as_int(OLDF), __float_as_int(SRCF), (CTRL), (RMASK), 0xF, false))

__device__ __forceinline__ float wave_max_u(float v) {
    v = fmaxf(v, DPP_F(-INFINITY, v, 0x111, 0xF));  // row_shr:1
    v = fmaxf(v, DPP_F(-INFINITY, v, 0x112, 0xF));  // row_shr:2
    v = fmaxf(v, DPP_F(-INFINITY, v, 0x114, 0xF));  // row_shr:4
    v = fmaxf(v, DPP_F(-INFINITY, v, 0x118, 0xF));  // row_shr:8
    v = fmaxf(v, DPP_F(-INFINITY, v, 0x142, 0xA));  // row_bcast:15 -> rows 1,3
    v = fmaxf(v, DPP_F(-INFINITY, v, 0x143, 0xC));  // row_bcast:31 -> rows 2,3
    return __int_as_float(__builtin_amdgcn_readlane(__float_as_int(v), 63)); // uniform (SGPR)
}
__device__ __forceinline__ float wave_sum_u(float v) {
    v = __fadd_rn(v, DPP_F(0.0f, v, 0x111, 0xF));
    v = __fadd_rn(v, DPP_F(0.0f, v, 0x112, 0xF));
    v = __fadd_rn(v, DPP_F(0.0f, v, 0x114, 0xF));
    v = __fadd_rn(v, DPP_F(0.0f, v, 0x118, 0xF));
    v = __fadd_rn(v, DPP_F(0.0f, v, 0x142, 0xA));
    v = __fadd_rn(v, DPP_F(0.0f, v, 0x143, 0xC));
    return __int_as_float(__builtin_amdgcn_readlane(__float_as_int(v), 63));
}

__global__ __launch_bounds__(BLOCK) void c51_kernel(
    const float* __restrict__ next_logits,   // [B,51]
    const float* __restrict__ old_logits,    // [B,4,51]
    const float* __restrict__ reward,        // [B]
    const float* __restrict__ done,          // [B]
    const int*   __restrict__ actions,       // [B]
    float* __restrict__ out,                 // out[0]=loss, out+1 = proj [B,51]
    int B)
{
    __shared__ float bins[WPB][RPI][64];
    __shared__ float wacc[WPB];

    const int lane  = threadIdx.x & 63;
    const int wid   = threadIdx.x >> 6;
    const int gwave = blockIdx.x * WPB + wid;
    const int nwav  = GRID * WPB;            // 8192 waves

    const float delta_z = 0.4f;
    const bool  active  = lane < N_ATOMS;
    // support z_j = VMIN + delta_z*j  (bit-exact vs numpy f32 op order — do not touch)
    const float zj = __fadd_rn(VMIN_F, __fmul_rn(delta_z, (float)lane));

    float acc = 0.0f;                        // per-lane CE partial (reduced once at end)

    const int stride = nwav * RPI;           // 16384 rows per grid-iteration
    const int iters  = (B + stride - 1) / stride;   // 32 for B=524288 (exact)

    for (int it = 0; it < iters; ++it) {
        const int  r0 = (gwave + it * nwav) * RPI;
        const int  r1 = r0 + 1;
        const bool vA = r0 < B, vB = r1 < B;

        // ---- issue ALL independent loads up front (overlap actions->old chain) ----
        float xA = (vA && active) ? next_logits[(size_t)r0 * N_ATOMS + lane] : -INFINITY;
        float xB = (vB && active) ? next_logits[(size_t)r1 * N_ATOMS + lane] : -INFINITY;
        float rwA = vA ? reward[r0] : 0.0f;
        float rwB = vB ? reward[r1] : 0.0f;
        float dnA = vA ? done[r0] : 1.0f;
        float dnB = vB ? done[r1] : 1.0f;
        int   aA  = vA ? actions[r0] : 0;
        int   aB  = vB ? actions[r1] : 0;
        float yA = (vA && active) ? old_logits[((size_t)r0 * ACT + aA) * N_ATOMS + lane] : -INFINITY;
        float yB = (vB && active) ? old_logits[((size_t)r1 * ACT + aB) * N_ATOMS + lane] : -INFINITY;

        // ---- softmax(next) x2, DPP reductions ----
        float mA = wave_max_u(xA);
        float mB = wave_max_u(xB);
        float eA = (vA && active) ? __expf(__fsub_rn(xA, mA)) : 0.0f;
        float eB = (vB && active) ? __expf(__fsub_rn(xB, mB)) : 0.0f;
        float sA = wave_sum_u(eA);
        float sB = wave_sum_u(eB);
        // p only scales weights (continuous path) — fast rcp is fine (~1ulp)
        float pA = __fmul_rn(eA, __builtin_amdgcn_rcpf(sA));
        float pB = __fmul_rn(eB, __builtin_amdgcn_rcpf(sB));

        // ---- Bellman projection: b-path is bit-exact f32 (frozen; decides floor/ceil) ----
        float s1A = __fmul_rn(__fsub_rn(1.0f, (dnA > 0.95f) ? 1.0f : 0.0f), GAMMA_F);
        float s1B = __fmul_rn(__fsub_rn(1.0f, (dnB > 0.95f) ? 1.0f : 0.0f), GAMMA_F);
        float tzA = __fadd_rn(rwA, __fmul_rn(s1A, zj));
        float tzB = __fadd_rn(rwB, __fmul_rn(s1B, zj));
        tzA = fminf(fmaxf(tzA, VMIN_F), VMAX_F);
        tzB = fminf(fmaxf(tzB, VMIN_F), VMAX_F);
        float bA = __fdiv_rn(__fsub_rn(tzA, VMIN_F), delta_z);
        float bB = __fdiv_rn(__fsub_rn(tzB, VMIN_F), delta_z);
        float lfA = floorf(bA), ufA = ceilf(bA);
        float lfB = floorf(bB), ufB = ceilf(bB);
        int liA = (int)lfA, uiA = (int)ufA;
        int liB = (int)lfB, uiB = (int)ufB;
        float wlA = __fmul_rn(pA, __fsub_rn(ufA, bA));
        float wuA = __fmul_rn(pA, __fsub_rn(bA, lfA));
        float wlB = __fmul_rn(pB, __fsub_rn(ufB, bB));
        float wuB = __fmul_rn(pB, __fsub_rn(bB, lfB));

        // ---- per-wave LDS scatter; wave-internal ordering only -> no __syncthreads ----
        bins[wid][0][lane] = 0.0f;
        bins[wid][1][lane] = 0.0f;
        asm volatile("s_waitcnt lgkmcnt(0)" ::: "memory");
        if (active) {
            if (vA) { atomicAdd(&bins[wid][0][liA], wlA); atomicAdd(&bins[wid][0][uiA], wuA); }
            if (vB) { atomicAdd(&bins[wid][1][liB], wlB); atomicAdd(&bins[wid][1][uiB], wuB); }
        }
        asm volatile("s_waitcnt lgkmcnt(0)" ::: "memory");
        float prA = bins[wid][0][lane];   // bins[51..63] stay 0
        float prB = bins[wid][1][lane];

        // ---- log_softmax(old row) x2 ----
        float m2A = wave_max_u(yA);
        float m2B = wave_max_u(yB);
        float shA = __fsub_rn(yA, m2A);
        float shB = __fsub_rn(yB, m2B);
        float e2A = (vA && active) ? __expf(shA) : 0.0f;
        float e2B = (vB && active) ? __expf(shB) : 0.0f;
        float s2A = wave_sum_u(e2A);
        float s2B = wave_sum_u(e2B);
        float lpA = __fsub_rn(shA, __logf(s2A));
        float lpB = __fsub_rn(shB, __logf(s2B));

        // per-lane CE accumulation (no per-row reduction)
        if (vA && active) acc = __fadd_rn(acc, __fmul_rn(prA, lpA));
        if (vB && active) acc = __fadd_rn(acc, __fmul_rn(prB, lpB));

        // ---- write proj rows (coalesced, adjacent rows) ----
        if (vA && active) out[1 + (size_t)r0 * N_ATOMS + lane] = prA;
        if (vB && active) out[1 + (size_t)r1 * N_ATOMS + lane] = prB;
    }

    // ---- loss: wave DPP-sum -> block LDS -> one global atomic ----
    float tot = wave_sum_u(acc);
    if (lane == 0) wacc[wid] = tot;
    __syncthreads();
    if (threadIdx.x == 0) {
        float t = 0.0f;
#pragma unroll
        for (int i = 0; i < WPB; ++i) t = __fadd_rn(t, wacc[i]);
        atomicAdd(out, -t / (float)B);
    }
}

extern "C" void kernel_launch(void* const* d_in, const int* in_sizes, int n_in,
                              void* d_out, int out_size, void* d_ws, size_t ws_size,
                              hipStream_t stream) {
    const float* next_logits = (const float*)d_in[0];
    const float* old_logits  = (const float*)d_in[1];
    const float* reward      = (const float*)d_in[2];
    const float* done        = (const float*)d_in[3];
    const int*   actions     = (const int*)d_in[4];
    float* out = (float*)d_out;
    const int B = in_sizes[2];   // reward element count

    hipMemsetAsync(d_out, 0, sizeof(float), stream);  // loss accumulator slot

    c51_kernel<<<GRID, BLOCK, 0, stream>>>(next_logits, old_logits, reward,
                                           done, actions, out, B);
}